// Round 11
// baseline (16.267 us; speedup 1.0000x reference)
//
#include <hip/hip_runtime.h>
#include <hip/hip_bf16.h>

// BatchAllTripletLoss, B=512, E=128, labels in [0,64), MARGIN=1.0, EPS=1e-16.
// K1 dist_mfma:  D[i][j] = max(n_i + n_j - 2 e_i.e_j, 0) via bf16 MFMA
//                (proven R10). PLUS: each block computes positive-list meta
//                for its 2 anchors (ballot + rank compaction) ->
//                meta[a*64+0]=np, meta[a*64+1+i]=plist[i]. Uniform work.
// K2 hinge_pass: 256 blocks, 2 anchors each, ONE data sync: waves 0/1
//                broadcast-gather pd[i]=D[a][plist[i]]; all threads read
//                their float2 of both D rows + int2 labels; hinge; reduce;
//                one partial per block. No ballots/compaction here.
// K3 finalize:   1 block reduces 256 partials.
// No atomics anywhere -> deterministic.

#define BSZ 512
#define EDIM 128
#define TS 32
#define NPOS 64   // meta stride: [np, plist[0..62]]

typedef __attribute__((ext_vector_type(8))) short short8;
typedef __attribute__((ext_vector_type(4))) float f32x4;

__device__ __forceinline__ unsigned short f2bf(float f) {
    __hip_bfloat16 h = __float2bfloat16(f);
    return *reinterpret_cast<unsigned short*>(&h);
}

__global__ __launch_bounds__(256) void dist_mfma(
    const float* __restrict__ embs,
    const int* __restrict__ labels,
    float* __restrict__ D,
    int* __restrict__ meta)
{
    __shared__ unsigned short Abf[TS][136];
    __shared__ unsigned short Bbf[TS][136];   // holds -2*b (exact scale)
    __shared__ float nA[TS], nB[TS];
    __shared__ int   lab[BSZ];
    __shared__ unsigned long long m0sh[8], m1sh[8];

    const int tid = threadIdx.x;
    const int bi = blockIdx.x >> 4;
    const int bj = blockIdx.x & 15;
    const int I = bi * TS, J = bj * TS;
    const int wv = tid >> 6, lane = tid & 63;
    const int a0 = blockIdx.x * 2, a1 = a0 + 1;

    const float4* E4 = reinterpret_cast<const float4*>(embs);

    // ---- stage fp32 -> bf16 LDS + exact fp32 norms + labels ----
#pragma unroll
    for (int q = 0; q < 4; ++q) {
        int idx = tid + 256 * q;
        int r   = idx >> 5;
        int k4  = idx & 31;

        float4 va = E4[(size_t)(I + r) * (EDIM / 4) + k4];
        float sa = va.x * va.x + va.y * va.y + va.z * va.z + va.w * va.w;
        sa += __shfl_xor(sa, 1); sa += __shfl_xor(sa, 2); sa += __shfl_xor(sa, 4);
        sa += __shfl_xor(sa, 8); sa += __shfl_xor(sa, 16);
        if ((tid & 31) == 0) nA[r] = sa;
        ushort4 ua = { f2bf(va.x), f2bf(va.y), f2bf(va.z), f2bf(va.w) };
        *reinterpret_cast<ushort4*>(&Abf[r][k4 * 4]) = ua;

        float4 vb = E4[(size_t)(J + r) * (EDIM / 4) + k4];
        float sb = vb.x * vb.x + vb.y * vb.y + vb.z * vb.z + vb.w * vb.w;
        sb += __shfl_xor(sb, 1); sb += __shfl_xor(sb, 2); sb += __shfl_xor(sb, 4);
        sb += __shfl_xor(sb, 8); sb += __shfl_xor(sb, 16);
        if ((tid & 31) == 0) nB[r] = sb;
        ushort4 ub = { f2bf(-2.f * vb.x), f2bf(-2.f * vb.y),
                       f2bf(-2.f * vb.z), f2bf(-2.f * vb.w) };
        *reinterpret_cast<ushort4*>(&Bbf[r][k4 * 4]) = ub;
    }
    lab[tid]       = labels[tid];
    lab[tid + 256] = labels[tid + 256];
    __syncthreads();

    // ---- ballots for this block's 2 meta-anchors ----
    const int la0 = lab[a0], la1 = lab[a1];
#pragma unroll
    for (int c = 0; c < 2; ++c) {
        int j = c * 256 + tid;
        unsigned long long m0 = __ballot(lab[j] == la0 && j != a0);
        unsigned long long m1 = __ballot(lab[j] == la1 && j != a1);
        if (lane == 0) { m0sh[c * 4 + wv] = m0; m1sh[c * 4 + wv] = m1; }
    }
    __syncthreads();

    // ---- MFMA quadrant (wv): acc init = nA[row]+nB[col] ----
    const int qi = wv >> 1, qj = wv & 1;
    const int l15 = lane & 15, lk = lane >> 4;

    f32x4 acc;
#pragma unroll
    for (int reg = 0; reg < 4; ++reg)
        acc[reg] = nA[qi * 16 + lk * 4 + reg] + nB[qj * 16 + l15];

    const unsigned short* arow = &Abf[qi * 16 + l15][0];
    const unsigned short* brow = &Bbf[qj * 16 + l15][0];
#pragma unroll
    for (int ks = 0; ks < 4; ++ks) {
        short8 af = *reinterpret_cast<const short8*>(arow + ks * 32 + lk * 8);
        short8 bf = *reinterpret_cast<const short8*>(brow + ks * 32 + lk * 8);
        acc = __builtin_amdgcn_mfma_f32_16x16x32_bf16(af, bf, acc, 0, 0, 0);
    }
#pragma unroll
    for (int reg = 0; reg < 4; ++reg) {
        int row = I + qi * 16 + lk * 4 + reg;
        int col = J + qj * 16 + l15;
        D[(size_t)row * BSZ + col] = fmaxf(acc[reg], 0.f);
    }

    // ---- meta compaction (rank via popcount) ----
    int np0 = 0, np1 = 0;
#pragma unroll
    for (int m = 0; m < 8; ++m) { np0 += __popcll(m0sh[m]); np1 += __popcll(m1sh[m]); }
    if (np0 > NPOS - 1) np0 = NPOS - 1;
    if (np1 > NPOS - 1) np1 = NPOS - 1;

#pragma unroll
    for (int c = 0; c < 2; ++c) {
        int j = c * 256 + tid;
        if (lab[j] == la0 && j != a0) {
            int mi = c * 4 + wv, off = 0;
            for (int m = 0; m < mi; ++m) off += __popcll(m0sh[m]);
            off += __popcll(m0sh[mi] & ((1ull << lane) - 1ull));
            if (off < NPOS - 1) meta[a0 * NPOS + 1 + off] = j;
        }
        if (lab[j] == la1 && j != a1) {
            int mi = c * 4 + wv, off = 0;
            for (int m = 0; m < mi; ++m) off += __popcll(m1sh[m]);
            off += __popcll(m1sh[mi] & ((1ull << lane) - 1ull));
            if (off < NPOS - 1) meta[a1 * NPOS + 1 + off] = j;
        }
    }
    if (tid == 0) { meta[a0 * NPOS] = np0; meta[a1 * NPOS] = np1; }
}

__global__ __launch_bounds__(256) void hinge_pass(
    const float* __restrict__ D,
    const int* __restrict__ labels,
    const int* __restrict__ meta,
    float* __restrict__ sums,
    float* __restrict__ cnts)
{
    __shared__ float pd0[NPOS], pd1[NPOS];
    __shared__ int   npsh[2];
    __shared__ float wsum[4];
    __shared__ int   wcnt[4];

    const int tid = threadIdx.x;
    const int wv = tid >> 6, lane = tid & 63;
    const int b = blockIdx.x, a0 = 2 * b, a1 = a0 + 1;

    // waves 0/1: gather positive distances via meta
    if (wv == 0) {
        int v = meta[a0 * NPOS + lane];
        int np = __shfl(v, 0);
        if (lane == 0) npsh[0] = np;
        if (lane >= 1 && lane <= np) pd0[lane - 1] = D[(size_t)a0 * BSZ + v];
    } else if (wv == 1) {
        int v = meta[a1 * NPOS + lane];
        int np = __shfl(v, 0);
        if (lane == 0) npsh[1] = np;
        if (lane >= 1 && lane <= np) pd1[lane - 1] = D[(size_t)a1 * BSZ + v];
    }

    const int la0 = labels[a0], la1 = labels[a1];
    int2   ln = reinterpret_cast<const int2*>(labels)[tid];
    float2 r0 = reinterpret_cast<const float2*>(D + (size_t)a0 * BSZ)[tid];
    float2 r1 = reinterpret_cast<const float2*>(D + (size_t)a1 * BSZ)[tid];
    __syncthreads();

    const int np0 = npsh[0], np1 = npsh[1];
    float s = 0.f;
    int   c = 0;
    if (ln.x != la0) for (int i = 0; i < np0; ++i) { float t = fmaxf(pd0[i] - r0.x + 1.0f, 0.f); s += t; c += (t > 1e-16f); }
    if (ln.y != la0) for (int i = 0; i < np0; ++i) { float t = fmaxf(pd0[i] - r0.y + 1.0f, 0.f); s += t; c += (t > 1e-16f); }
    if (ln.x != la1) for (int i = 0; i < np1; ++i) { float t = fmaxf(pd1[i] - r1.x + 1.0f, 0.f); s += t; c += (t > 1e-16f); }
    if (ln.y != la1) for (int i = 0; i < np1; ++i) { float t = fmaxf(pd1[i] - r1.y + 1.0f, 0.f); s += t; c += (t > 1e-16f); }

#pragma unroll
    for (int off = 32; off; off >>= 1) {
        s += __shfl_down(s, off);
        c += __shfl_down(c, off);
    }
    if (lane == 0) { wsum[wv] = s; wcnt[wv] = c; }
    __syncthreads();
    if (tid == 0) {
        sums[b] = wsum[0] + wsum[1] + wsum[2] + wsum[3];
        cnts[b] = (float)(wcnt[0] + wcnt[1] + wcnt[2] + wcnt[3]);
    }
}

__global__ __launch_bounds__(256) void finalize(
    const float* __restrict__ sums,
    const float* __restrict__ cnts,
    float* __restrict__ out)
{
    __shared__ float fsum[4], fcnt[4];
    const int tid = threadIdx.x;
    float s = sums[tid];
    float c = cnts[tid];
#pragma unroll
    for (int off = 32; off; off >>= 1) {
        s += __shfl_down(s, off);
        c += __shfl_down(c, off);
    }
    const int wv = tid >> 6, lane = tid & 63;
    if (lane == 0) { fsum[wv] = s; fcnt[wv] = c; }
    __syncthreads();
    if (tid == 0) {
        float S = fsum[0] + fsum[1] + fsum[2] + fsum[3];
        float C = fcnt[0] + fcnt[1] + fcnt[2] + fcnt[3];
        out[0] = S / (C + 1e-16f);
    }
}

extern "C" void kernel_launch(void* const* d_in, const int* in_sizes, int n_in,
                              void* d_out, int out_size, void* d_ws, size_t ws_size,
                              hipStream_t stream)
{
    const float* embs   = reinterpret_cast<const float*>(d_in[0]);
    const int*   labels = reinterpret_cast<const int*>(d_in[1]);
    float*       out    = reinterpret_cast<float*>(d_out);

    float* D    = reinterpret_cast<float*>(d_ws);                 // 1 MB
    int*   meta = reinterpret_cast<int*>(D + (size_t)BSZ * BSZ);  // 512*64*4 = 128 KB
    float* sums = reinterpret_cast<float*>(meta + BSZ * NPOS);    // 1 KB
    float* cnts = sums + 256;                                     // 1 KB

    dist_mfma<<<256, 256, 0, stream>>>(embs, labels, D, meta);
    hinge_pass<<<256, 256, 0, stream>>>(D, labels, meta, sums, cnts);
    finalize<<<1, 256, 0, stream>>>(sums, cnts, out);
}